// Round 1
// baseline (105.649 us; speedup 1.0000x reference)
//
#include <hip/hip_runtime.h>

typedef _Float16 f16x8 __attribute__((ext_vector_type(8)));
typedef float    f32x4 __attribute__((ext_vector_type(4)));

constexpr int NTOK   = 1568;   // T*H*W = 8*14*14
constexpr int NHEADS = 8;
constexpr int NCH    = 512;
constexpr int KBLK   = 64;
constexpr int QBLK   = 64;
constexpr int PAD    = 72;     // 64 + 8 f16 pad: breaks 128B-stride bank conflicts, keeps 16B align

__global__ __launch_bounds__(256)
void attn_fwd(const float* __restrict__ x, float* __restrict__ out)
{
    const int qt   = blockIdx.x;        // 0..24
    const int bh   = blockIdx.y;        // 0..31
    const int b    = bh >> 3;
    const int head = bh & 7;
    const int tid  = threadIdx.x;
    const int wave = tid >> 6;
    const int lane = tid & 63;
    const int l15  = lane & 15;
    const int grp  = lane >> 4;

    __shared__ _Float16 kt[KBLK][PAD];    // K tile  [tok][dim]   (also V, unscaled)
    __shared__ _Float16 vt[64][PAD];      // V^T tile [dim][tok]  (for contiguous PV B-frags)
    __shared__ _Float16 pl[4][16][PAD];   // per-wave P [qrow][tok]

    const float* __restrict__ xb = x + (size_t)b * NCH * NTOK;

    // ---- Q fragment (A operand), scaled by 1/64 (exact pow2; matches (q*s)@(k*s)) ----
    const int qrow = qt * QBLK + wave * 16 + l15;
    const int qrc  = qrow < NTOK ? qrow : NTOK - 1;
    f16x8 aq[2];
#pragma unroll
    for (int ks = 0; ks < 2; ++ks)
#pragma unroll
        for (int j = 0; j < 8; ++j) {
            const int dim = ks * 32 + 8 * grp + j;
            aq[ks][j] = (_Float16)(xb[(dim * NHEADS + head) * NTOK + qrc] * 0.015625f);
        }

    const f32x4 zero4 = {0.f, 0.f, 0.f, 0.f};
    f32x4 oacc[4];
#pragma unroll
    for (int db = 0; db < 4; ++db) oacc[db] = zero4;
    float mrun[4], lrun[4];
#pragma unroll
    for (int r = 0; r < 4; ++r) { mrun[r] = -1e30f; lrun[r] = 0.f; }

    const int stok = tid & 63;   // staging: token = lane
    const int sdg  = tid >> 6;   // staging: each wave covers 16 dims

    constexpr int NKT = (NTOK + KBLK - 1) / KBLK;   // 25 (24 full + one 32-token tail)
    for (int t = 0; t < NKT; ++t) {
        const int kbase  = t * KBLK;
        const int kvalid = (NTOK - kbase < KBLK) ? (NTOK - kbase) : KBLK;  // 64 or 32
        const int ncb    = kvalid >> 4;   // 16-col blocks of S
        const int nks    = kvalid >> 5;   // 32-k steps for PV

        __syncthreads();   // previous tile fully consumed
        {   // ---- stage K/V tile: coalesced 256B global loads, LDS in both layouts ----
            int gidx = kbase + stok; if (gidx >= NTOK) gidx = NTOK - 1;
            f16x8 h0, h1;
#pragma unroll
            for (int i = 0; i < 8; ++i)
                h0[i] = (_Float16)xb[((sdg * 16 + i) * NHEADS + head) * NTOK + gidx];
#pragma unroll
            for (int i = 0; i < 8; ++i)
                h1[i] = (_Float16)xb[((sdg * 16 + 8 + i) * NHEADS + head) * NTOK + gidx];
            *(f16x8*)&kt[stok][sdg * 16]     = h0;
            *(f16x8*)&kt[stok][sdg * 16 + 8] = h1;
#pragma unroll
            for (int i = 0; i < 8; ++i) vt[sdg * 16 + i][stok]     = h0[i];
#pragma unroll
            for (int i = 0; i < 8; ++i) vt[sdg * 16 + 8 + i][stok] = h1[i];
        }
        __syncthreads();

        // ---- S = (Q/64) K^T : D-layout = (row q = 4*grp+r, col tok = cb*16+l15) ----
        f32x4 sacc[4];
#pragma unroll
        for (int cb = 0; cb < 4; ++cb) sacc[cb] = zero4;
#pragma unroll
        for (int cb = 0; cb < 4; ++cb) {
            if (cb < ncb) {
#pragma unroll
                for (int ks = 0; ks < 2; ++ks) {
                    f16x8 bk = *(const f16x8*)&kt[cb * 16 + l15][ks * 32 + 8 * grp];
                    sacc[cb] = __builtin_amdgcn_mfma_f32_16x16x32_f16(aq[ks], bk, sacc[cb], 0, 0, 0);
                }
            }
        }

        // ---- online softmax (row reduce across the 16 lanes of each group) ----
        float rmax[4];
#pragma unroll
        for (int r = 0; r < 4; ++r) {
            float v = sacc[0][r];
#pragma unroll
            for (int cb = 1; cb < 4; ++cb) if (cb < ncb) v = fmaxf(v, sacc[cb][r]);
            rmax[r] = v;
        }
#pragma unroll
        for (int r = 0; r < 4; ++r)
#pragma unroll
            for (int m = 1; m < 16; m <<= 1)
                rmax[r] = fmaxf(rmax[r], __shfl_xor(rmax[r], m));

        float corr[4], rsum[4];
#pragma unroll
        for (int r = 0; r < 4; ++r) {
            const float mnew = fmaxf(mrun[r], rmax[r]);
            corr[r] = __expf(mrun[r] - mnew);
            mrun[r] = mnew;
            rsum[r] = 0.f;
        }
#pragma unroll
        for (int cb = 0; cb < 4; ++cb) {
            if (cb < ncb) {
#pragma unroll
                for (int r = 0; r < 4; ++r) {
                    const float p = __expf(sacc[cb][r] - mrun[r]);
                    rsum[r] += p;
                    pl[wave][4 * grp + r][cb * 16 + l15] = (_Float16)p;
                }
            }
        }
#pragma unroll
        for (int r = 0; r < 4; ++r)
#pragma unroll
            for (int m = 1; m < 16; m <<= 1)
                rsum[r] += __shfl_xor(rsum[r], m);
#pragma unroll
        for (int r = 0; r < 4; ++r) lrun[r] = lrun[r] * corr[r] + rsum[r];
#pragma unroll
        for (int db = 0; db < 4; ++db)
#pragma unroll
            for (int r = 0; r < 4; ++r) oacc[db][r] *= corr[r];

        // ---- O += P V  (A = P from per-wave LDS, B = V^T rows: contiguous b128) ----
        f16x8 ap[2];
        ap[0] = *(const f16x8*)&pl[wave][l15][8 * grp];
        if (nks == 2) ap[1] = *(const f16x8*)&pl[wave][l15][32 + 8 * grp];
#pragma unroll
        for (int db = 0; db < 4; ++db) {
#pragma unroll
            for (int ks = 0; ks < 2; ++ks) {
                if (ks < nks) {
                    f16x8 bv = *(const f16x8*)&vt[db * 16 + l15][ks * 32 + 8 * grp];
                    oacc[db] = __builtin_amdgcn_mfma_f32_16x16x32_f16(ap[ks], bv, oacc[db], 0, 0, 0);
                }
            }
        }
    }

    // ---- epilogue: O / l, packed float4 store (4 consecutive n per lane) ----
    if (qt * QBLK + wave * 16 < NTOK) {      // wave-uniform validity (N % 16 == 0)
        const int n0 = qt * QBLK + wave * 16 + 4 * grp;
#pragma unroll
        for (int db = 0; db < 4; ++db) {
            f32x4 o;
            o[0] = oacc[db][0] / lrun[0];
            o[1] = oacc[db][1] / lrun[1];
            o[2] = oacc[db][2] / lrun[2];
            o[3] = oacc[db][3] / lrun[3];
            const int ch = (db * 16 + l15) * NHEADS + head;
            *(f32x4*)&out[(b * NCH + ch) * NTOK + n0] = o;
        }
    }
}

extern "C" void kernel_launch(void* const* d_in, const int* in_sizes, int n_in,
                              void* d_out, int out_size, void* d_ws, size_t ws_size,
                              hipStream_t stream)
{
    const float* x = (const float*)d_in[0];
    float* out     = (float*)d_out;
    dim3 grid((NTOK + QBLK - 1) / QBLK, 4 * NHEADS);   // 25 x 32
    attn_fwd<<<grid, 256, 0, stream>>>(x, out);
}